// Round 1
// baseline (118.291 us; speedup 1.0000x reference)
//
#include <hip/hip_runtime.h>
#include <math.h>

#define BATCH 8192
#define DIM   2048

// One wave (64 lanes) per batch row. Each lane reduces timesteps
// [32*lane, 32*lane+32) to a 3x3 transfer matrix in linear space with a
// log-scale accumulator, then an ordered shfl_down tree combines the 64
// chunk matrices (semiring matmul is associative). Lane 0 applies the
// start vector and writes the row's log-prob.
__global__ __launch_bounds__(256, 4)
void hmm_fwd(const int* __restrict__ y,
             const float* __restrict__ tp,
             const float* __restrict__ ep,
             const float* __restrict__ sp,
             float* __restrict__ row_lp,   // [BATCH] or nullptr
             float* __restrict__ out_atomic)
{
    const int lane = threadIdx.x & 63;
    const int wid  = threadIdx.x >> 6;
    const int b    = blockIdx.x * 4 + wid;

    // ---- parameters (redundant per thread; ~60 VALU ops total) ----
    float T[3][3], E[3][2], pi[3];
    #pragma unroll
    for (int i = 0; i < 3; ++i) {
        float a0 = tp[i*3+0], a1 = tp[i*3+1], a2 = tp[i*3+2];
        float mx = fmaxf(a0, fmaxf(a1, a2));
        float e0 = __expf(a0-mx), e1 = __expf(a1-mx), e2 = __expf(a2-mx);
        float inv = 1.0f / (e0+e1+e2);
        T[i][0] = e0*inv; T[i][1] = e1*inv; T[i][2] = e2*inv;
    }
    #pragma unroll
    for (int s = 0; s < 3; ++s) {
        float a0 = ep[s*2+0], a1 = ep[s*2+1];
        float mx = fmaxf(a0, a1);
        float e0 = __expf(a0-mx), e1 = __expf(a1-mx);
        float inv = 1.0f / (e0+e1);
        E[s][0] = e0*inv; E[s][1] = e1*inv;
    }
    {
        float a0 = sp[0], a1 = sp[1], a2 = sp[2];
        float mx = fmaxf(a0, fmaxf(a1, a2));
        float e0 = __expf(a0-mx), e1 = __expf(a1-mx), e2 = __expf(a2-mx);
        float inv = 1.0f / (e0+e1+e2);
        pi[0] = e0*inv; pi[1] = e1*inv; pi[2] = e2*inv;
    }
    // TEy[k][j] = T[k][j] * E[j][y]  (per-timestep transfer matrix, y in {0,1})
    float TE0[3][3], TE1[3][3];
    #pragma unroll
    for (int k = 0; k < 3; ++k)
        #pragma unroll
        for (int j = 0; j < 3; ++j) {
            TE0[k][j] = T[k][j] * E[j][0];
            TE1[k][j] = T[k][j] * E[j][1];
        }

    const int* __restrict__ yb = y + (size_t)b * DIM;

    float R[3][3] = {{1.f,0.f,0.f},{0.f,1.f,0.f},{0.f,0.f,1.f}};
    float lsc = 0.0f;

    auto step = [&](int yv) {
        const bool one = (yv != 0);
        float nR[3][3];
        #pragma unroll
        for (int j = 0; j < 3; ++j) {
            float m0 = one ? TE1[0][j] : TE0[0][j];
            float m1 = one ? TE1[1][j] : TE0[1][j];
            float m2 = one ? TE1[2][j] : TE0[2][j];
            #pragma unroll
            for (int i = 0; i < 3; ++i)
                nR[i][j] = fmaf(R[i][0], m0, fmaf(R[i][1], m1, R[i][2]*m2));
        }
        #pragma unroll
        for (int i = 0; i < 3; ++i)
            #pragma unroll
            for (int j = 0; j < 3; ++j)
                R[i][j] = nR[i][j];
    };

    auto rescale = [&]() {
        float m = R[0][0];
        #pragma unroll
        for (int i = 0; i < 3; ++i)
            #pragma unroll
            for (int j = 0; j < 3; ++j)
                m = fmaxf(m, R[i][j]);
        lsc += __logf(m);
        float inv = 1.0f / m;
        #pragma unroll
        for (int i = 0; i < 3; ++i)
            #pragma unroll
            for (int j = 0; j < 3; ++j)
                R[i][j] *= inv;
    };

    const int tbase = lane * 32;
    #pragma unroll
    for (int g = 0; g < 8; ++g) {
        int4 q = *reinterpret_cast<const int4*>(yb + tbase + 4*g);
        if (g == 0) {
            if (lane != 0) step(q.x);   // t==0 belongs to the start vector
            step(q.y); step(q.z); step(q.w);
        } else {
            step(q.x); step(q.y); step(q.z); step(q.w);
        }
        if (g == 3 || g == 7) rescale();
    }

    // ---- ordered wave reduction: R_lane = R_lane @ R_{lane+offset} ----
    #pragma unroll
    for (int o = 1; o < 64; o <<= 1) {
        float S[3][3];
        #pragma unroll
        for (int i = 0; i < 3; ++i)
            #pragma unroll
            for (int j = 0; j < 3; ++j)
                S[i][j] = __shfl_down(R[i][j], o, 64);
        float osc = __shfl_down(lsc, o, 64);
        float nR[3][3];
        #pragma unroll
        for (int i = 0; i < 3; ++i)
            #pragma unroll
            for (int j = 0; j < 3; ++j)
                nR[i][j] = fmaf(R[i][0], S[0][j], fmaf(R[i][1], S[1][j], R[i][2]*S[2][j]));
        #pragma unroll
        for (int i = 0; i < 3; ++i)
            #pragma unroll
            for (int j = 0; j < 3; ++j)
                R[i][j] = nR[i][j];
        lsc += osc;
    }

    if (lane == 0) {
        int y0 = yb[0];
        float a0 = pi[0] * (y0 ? E[0][1] : E[0][0]);
        float a1 = pi[1] * (y0 ? E[1][1] : E[1][0]);
        float a2 = pi[2] * (y0 ? E[2][1] : E[2][0]);
        float p = 0.0f;
        #pragma unroll
        for (int j = 0; j < 3; ++j)
            p += fmaf(a0, R[0][j], fmaf(a1, R[1][j], a2 * R[2][j]));
        float lp = __logf(p) + lsc;
        if (row_lp) row_lp[b] = lp;
        else        atomicAdd(out_atomic, lp * (1.0f / BATCH));
    }
}

__global__ void reduce_mean(const float* __restrict__ row, float* __restrict__ out)
{
    float s = 0.0f;
    for (int i = threadIdx.x; i < BATCH; i += 256) s += row[i];
    #pragma unroll
    for (int o = 32; o > 0; o >>= 1) s += __shfl_down(s, o, 64);
    __shared__ float sm[4];
    int w = threadIdx.x >> 6;
    if ((threadIdx.x & 63) == 0) sm[w] = s;
    __syncthreads();
    if (threadIdx.x == 0) out[0] = (sm[0] + sm[1] + sm[2] + sm[3]) * (1.0f / BATCH);
}

extern "C" void kernel_launch(void* const* d_in, const int* in_sizes, int n_in,
                              void* d_out, int out_size, void* d_ws, size_t ws_size,
                              hipStream_t stream)
{
    const int*   y  = (const int*)d_in[0];
    const float* tp = (const float*)d_in[1];
    const float* ep = (const float*)d_in[2];
    const float* sp = (const float*)d_in[3];
    float* out = (float*)d_out;

    const bool use_ws = (ws_size >= BATCH * sizeof(float));
    if (use_ws) {
        float* row = (float*)d_ws;
        hmm_fwd<<<BATCH/4, 256, 0, stream>>>(y, tp, ep, sp, row, nullptr);
        reduce_mean<<<1, 256, 0, stream>>>(row, out);
    } else {
        hipMemsetAsync(out, 0, sizeof(float), stream);
        hmm_fwd<<<BATCH/4, 256, 0, stream>>>(y, tp, ep, sp, nullptr, out);
    }
}

// Round 2
// 109.098 us; speedup vs baseline: 1.0843x; 1.0843x over previous
//
#include <hip/hip_runtime.h>
#include <math.h>

#define BATCH 8192
#define DIM   2048

// One wave (64 lanes) per batch row. Each lane reduces a 32-timestep chunk
// to a 3x3 transfer matrix. Since y is binary, 4 timesteps are folded into
// one matmul against a precomputed 16-entry LDS table of 4-step products
// (T4[y0+2y1+4y2+8y3] = M_{y0}M_{y1}M_{y2}M_{y3}); lane 0 uses an 8-entry
// 3-step table for its first group so t=0 (start-vector step) is skipped
// with no per-step branching. Ordered shfl_down tree combines the 64 chunk
// matrices; lane 0 applies the start vector and writes the row log-prob.
__global__ __launch_bounds__(256, 4)
void hmm_fwd(const int* __restrict__ y,
             const float* __restrict__ tp,
             const float* __restrict__ ep,
             const float* __restrict__ sp,
             float* __restrict__ row_lp,
             float* __restrict__ out_atomic)
{
    __shared__ float tbl[24 * 9];   // mats 0..15: 4-step; 16..23: 3-step

    const int tid  = threadIdx.x;
    const int lane = tid & 63;
    const int wid  = tid >> 6;
    const int b    = blockIdx.x * 4 + wid;

    // ---- normalized parameters (uniform; ~80 VALU once) ----
    float T[3][3], E[3][2], pi[3];
    #pragma unroll
    for (int i = 0; i < 3; ++i) {
        float a0 = tp[i*3+0], a1 = tp[i*3+1], a2 = tp[i*3+2];
        float mx = fmaxf(a0, fmaxf(a1, a2));
        float e0 = __expf(a0-mx), e1 = __expf(a1-mx), e2 = __expf(a2-mx);
        float inv = 1.0f / (e0+e1+e2);
        T[i][0] = e0*inv; T[i][1] = e1*inv; T[i][2] = e2*inv;
    }
    #pragma unroll
    for (int s = 0; s < 3; ++s) {
        float a0 = ep[s*2+0], a1 = ep[s*2+1];
        float mx = fmaxf(a0, a1);
        float e0 = __expf(a0-mx), e1 = __expf(a1-mx);
        float inv = 1.0f / (e0+e1);
        E[s][0] = e0*inv; E[s][1] = e1*inv;
    }
    {
        float a0 = sp[0], a1 = sp[1], a2 = sp[2];
        float mx = fmaxf(a0, fmaxf(a1, a2));
        float e0 = __expf(a0-mx), e1 = __expf(a1-mx), e2 = __expf(a2-mx);
        float inv = 1.0f / (e0+e1+e2);
        pi[0] = e0*inv; pi[1] = e1*inv; pi[2] = e2*inv;
    }

    // per-step matrices M_y[k*3+j] = T[k][j] * E[j][y]
    float M0[9], M1[9];
    #pragma unroll
    for (int k = 0; k < 3; ++k)
        #pragma unroll
        for (int j = 0; j < 3; ++j) {
            M0[k*3+j] = T[k][j] * E[j][0];
            M1[k*3+j] = T[k][j] * E[j][1];
        }

    // ---- build LDS product tables (threads 0..23) ----
    if (tid < 24) {
        int code, n;
        if (tid < 16) { code = tid;      n = 4; }
        else          { code = tid - 16; n = 3; }
        float A[9];
        {
            const float* F = (code & 1) ? M1 : M0;
            #pragma unroll
            for (int e = 0; e < 9; ++e) A[e] = F[e];
            code >>= 1;
        }
        for (int s = 1; s < n; ++s) {
            const float* F = (code & 1) ? M1 : M0;
            code >>= 1;
            float Z[9];
            #pragma unroll
            for (int i = 0; i < 3; ++i)
                #pragma unroll
                for (int j = 0; j < 3; ++j)
                    Z[i*3+j] = fmaf(A[i*3+0], F[0*3+j],
                               fmaf(A[i*3+1], F[1*3+j], A[i*3+2]*F[2*3+j]));
            #pragma unroll
            for (int e = 0; e < 9; ++e) A[e] = Z[e];
        }
        #pragma unroll
        for (int e = 0; e < 9; ++e) tbl[tid*9 + e] = A[e];
    }
    __syncthreads();

    // ---- main chunk reduction: 8 groups of 4 timesteps ----
    const int* __restrict__ yb = y + (size_t)b * DIM + lane * 32;

    float R[9] = {1.f,0.f,0.f, 0.f,1.f,0.f, 0.f,0.f,1.f};
    float lsc = 0.0f;
    int y0 = 0;

    #pragma unroll
    for (int g = 0; g < 8; ++g) {
        int4 q = *reinterpret_cast<const int4*>(yb + 4*g);
        int idx;
        if (g == 0) {
            y0 = q.x;
            int i4 = q.x + 2*q.y + 4*q.z + 8*q.w;
            int i3 = 16 + (q.y + 2*q.z + 4*q.w);
            idx = (lane == 0) ? i3 : i4;
        } else {
            idx = q.x + 2*q.y + 4*q.z + 8*q.w;
        }
        const float* __restrict__ G = &tbl[idx * 9];
        float g0 = G[0], g1 = G[1], g2 = G[2],
              g3 = G[3], g4 = G[4], g5 = G[5],
              g6 = G[6], g7 = G[7], g8 = G[8];
        float nR[9];
        #pragma unroll
        for (int i = 0; i < 3; ++i) {
            nR[i*3+0] = fmaf(R[i*3+0], g0, fmaf(R[i*3+1], g3, R[i*3+2]*g6));
            nR[i*3+1] = fmaf(R[i*3+0], g1, fmaf(R[i*3+1], g4, R[i*3+2]*g7));
            nR[i*3+2] = fmaf(R[i*3+0], g2, fmaf(R[i*3+1], g5, R[i*3+2]*g8));
        }
        #pragma unroll
        for (int e = 0; e < 9; ++e) R[e] = nR[e];

        if (g == 3 || g == 7) {
            float m = R[0];
            #pragma unroll
            for (int e = 1; e < 9; ++e) m = fmaxf(m, R[e]);
            lsc += __logf(m);
            float inv = 1.0f / m;
            #pragma unroll
            for (int e = 0; e < 9; ++e) R[e] *= inv;
        }
    }

    // ---- ordered wave reduction: R_lane = R_lane @ R_{lane+offset} ----
    #pragma unroll
    for (int o = 1; o < 64; o <<= 1) {
        float S[9];
        #pragma unroll
        for (int e = 0; e < 9; ++e) S[e] = __shfl_down(R[e], o, 64);
        float osc = __shfl_down(lsc, o, 64);
        float nR[9];
        #pragma unroll
        for (int i = 0; i < 3; ++i)
            #pragma unroll
            for (int j = 0; j < 3; ++j)
                nR[i*3+j] = fmaf(R[i*3+0], S[0*3+j],
                            fmaf(R[i*3+1], S[1*3+j], R[i*3+2]*S[2*3+j]));
        #pragma unroll
        for (int e = 0; e < 9; ++e) R[e] = nR[e];
        lsc += osc;
    }

    if (lane == 0) {
        float e0 = y0 ? E[0][1] : E[0][0];
        float e1 = y0 ? E[1][1] : E[1][0];
        float e2 = y0 ? E[2][1] : E[2][0];
        float a0 = pi[0] * e0, a1 = pi[1] * e1, a2 = pi[2] * e2;
        float p = 0.0f;
        #pragma unroll
        for (int j = 0; j < 3; ++j)
            p += fmaf(a0, R[0*3+j], fmaf(a1, R[1*3+j], a2 * R[2*3+j]));
        float lp = __logf(p) + lsc;
        if (row_lp) row_lp[b] = lp;
        else        atomicAdd(out_atomic, lp * (1.0f / BATCH));
    }
}

__global__ void reduce_mean(const float* __restrict__ row, float* __restrict__ out)
{
    float s = 0.0f;
    for (int i = threadIdx.x; i < BATCH; i += 256) s += row[i];
    #pragma unroll
    for (int o = 32; o > 0; o >>= 1) s += __shfl_down(s, o, 64);
    __shared__ float sm[4];
    int w = threadIdx.x >> 6;
    if ((threadIdx.x & 63) == 0) sm[w] = s;
    __syncthreads();
    if (threadIdx.x == 0) out[0] = (sm[0] + sm[1] + sm[2] + sm[3]) * (1.0f / BATCH);
}

extern "C" void kernel_launch(void* const* d_in, const int* in_sizes, int n_in,
                              void* d_out, int out_size, void* d_ws, size_t ws_size,
                              hipStream_t stream)
{
    const int*   y  = (const int*)d_in[0];
    const float* tp = (const float*)d_in[1];
    const float* ep = (const float*)d_in[2];
    const float* sp = (const float*)d_in[3];
    float* out = (float*)d_out;

    const bool use_ws = (ws_size >= BATCH * sizeof(float));
    if (use_ws) {
        float* row = (float*)d_ws;
        hmm_fwd<<<BATCH/4, 256, 0, stream>>>(y, tp, ep, sp, row, nullptr);
        reduce_mean<<<1, 256, 0, stream>>>(row, out);
    } else {
        hipMemsetAsync(out, 0, sizeof(float), stream);
        hmm_fwd<<<BATCH/4, 256, 0, stream>>>(y, tp, ep, sp, nullptr, out);
    }
}